// Round 10
// baseline (1086.727 us; speedup 1.0000x reference)
//
#include <hip/hip_runtime.h>
#include <math.h>

#define T_LEN 3000
#define EDGE 15
#define NF 97
#define NB 64
#define NH 256
#define NI 100
#define SEQ 6336       // Pt row width: 64 x-cols + 6208 filter cols
#define NSEQ (NF*NB)
#define KCO 32         // k_out K-chunk: 256 = 8*32
#define LDA 132        // k_out LDS row stride (floats)

// ---------------- Kernel 0: k_prep — x^T into Pt cols 0..63 + pseudo U row
__global__ __launch_bounds__(256) void k_prep(
    const float* __restrict__ x, const float* __restrict__ b1,
    const float* __restrict__ w2, float* __restrict__ Pt, float* __restrict__ U)
{
    const int kk0 = blockIdx.x * 64;
    const int b   = threadIdx.x & 63;
    const int ko  = threadIdx.x >> 6;     // 0..3
    #pragma unroll
    for (int p = 0; p < 16; ++p) {
        int kk = kk0 + ko + 4*p;
        if (kk < T_LEN) Pt[(size_t)kk*SEQ + b] = x[(size_t)b*T_LEN + kk];
    }
    if (blockIdx.x == 0) {
        int h = threadIdx.x;              // 256 threads = 256 h
        float th = tanhf(b1[h]);
        U[(size_t)6336*NH + h] = (1.f - th*th) * w2[h];
    }
}

// ---------------- Kernel 1: filtfilt on Pt (k-major, fully coalesced) -----
// lane = b, block = f. All global ops are 256B wave-coalesced. Edge y values
// live in registers (bwd at ext i<15 cannot affect kept outputs -> skipped).
// FSTEP chain identical to prior rounds => bit-identical output.
__global__ __launch_bounds__(64) void k_filtfilt(
    float* Pt, const float* __restrict__ b_all,
    const float* __restrict__ a_all, const float* __restrict__ zi_all)
{
    const int f    = blockIdx.x;
    const int lane = threadIdx.x;
    const double bc0 = b_all[f*5+0], bc1 = b_all[f*5+1], bc2 = b_all[f*5+2],
                 bc3 = b_all[f*5+3], bc4 = b_all[f*5+4];
    const double ac1 = a_all[f*5+1], ac2 = a_all[f*5+2],
                 ac3 = a_all[f*5+3], ac4 = a_all[f*5+4];
    const double zi0 = zi_all[f*4+0], zi1 = zi_all[f*4+1],
                 zi2 = zi_all[f*4+2], zi3 = zi_all[f*4+3];
    const float* xc = Pt + lane;                       // x column
    float*       yc = Pt + 64 + (size_t)f*64 + lane;   // y column

    double z0, z1, z2, z3;

#define FSTEP(XV, DST) { double xv = (XV); \
    double yv = fma(bc0, xv, z0); \
    z0 = fma(bc1, xv, z1) - ac1*yv; \
    z1 = fma(bc2, xv, z2) - ac2*yv; \
    z2 = fma(bc3, xv, z3) - ac3*yv; \
    z3 = bc4*xv - ac4*yv; \
    DST = (float)yv; }

    const double x0 = (double)xc[0];
    const double xl = (double)xc[(size_t)(T_LEN-1)*SEQ];
    { const double e0 = 2.0*x0 - (double)xc[(size_t)EDGE*SEQ];
      z0 = zi0*e0; z1 = zi1*e0; z2 = zi2*e0; z3 = zi3*e0; }

    // left edge (15 steps, state only — outputs never used)
    {
        float le[15];
        #pragma unroll
        for (int i = 0; i < 15; ++i) le[i] = xc[(size_t)(EDGE - i)*SEQ];
        #pragma unroll
        for (int i = 0; i < 15; ++i) { float o; FSTEP(2.0*x0 - (double)le[i], o); (void)o; }
    }
    // main fwd: kk = 0..2999 (ext i = kk+15), 150 chunks of 20, 1-ahead prefetch
    {
        float cur[20], nxt[20];
        #pragma unroll
        for (int j = 0; j < 20; ++j) cur[j] = xc[(size_t)j*SEQ];
        for (int kk = 0; kk < T_LEN; kk += 20) {
            if (kk + 20 < T_LEN) {
                #pragma unroll
                for (int j = 0; j < 20; ++j) nxt[j] = xc[(size_t)(kk+20+j)*SEQ];
            }
            #pragma unroll
            for (int j = 0; j < 20; ++j) {
                float o; FSTEP((double)cur[j], o); yc[(size_t)(kk+j)*SEQ] = o;
            }
            #pragma unroll
            for (int j = 0; j < 20; ++j) cur[j] = nxt[j];
        }
    }
    // right edge (ext i = 3015..3029): y kept in regs
    float yr[15];
    {
        float re[15];
        #pragma unroll
        for (int i = 0; i < 15; ++i) re[i] = xc[(size_t)(T_LEN-2-i)*SEQ];
        #pragma unroll
        for (int i = 0; i < 15; ++i) { float o; FSTEP(2.0*xl - (double)re[i], o); yr[i] = o; }
    }

    // backward pass (descending ext i), in place on yc
    const double yl = (double)yr[14];
    z0 = zi0*yl; z1 = zi1*yl; z2 = zi2*yl; z3 = zi3*yl;
    #pragma unroll
    for (int i = 14; i >= 0; --i) { float o; FSTEP((double)yr[i], o); (void)o; }
    {
        float bcur[20], bnxt[20];
        #pragma unroll
        for (int j = 0; j < 20; ++j) bcur[j] = yc[(size_t)(2980+j)*SEQ];
        for (int kt = 2980; kt >= 0; kt -= 20) {
            if (kt >= 20) {
                #pragma unroll
                for (int j = 0; j < 20; ++j) bnxt[j] = yc[(size_t)(kt-20+j)*SEQ];
            }
            #pragma unroll
            for (int j = 19; j >= 0; --j) { float o; FSTEP((double)bcur[j], o); bcur[j] = o; }
            #pragma unroll
            for (int j = 0; j < 20; ++j) yc[(size_t)(kt+j)*SEQ] = bcur[j];
            #pragma unroll
            for (int j = 0; j < 20; ++j) bcur[j] = bnxt[j];
        }
    }
#undef FSTEP
}

// ---------------- Kernel 2: U[r][h] — lanes=rows, W1 on scalar pipe -------
// 256 thr = 4 waves; wave handles 16 h (h0 uniform via readfirstlane).
// P: coalesced vector dword per k. W1: uniform s_load (K$-hot 3MB).
// No LDS, no barriers. K ascending, same fmaf chain => bit-identical.
__global__ __launch_bounds__(256) void k_ugemm(
    const float* __restrict__ Pt, const float* __restrict__ W1,
    const float* __restrict__ b1, const float* __restrict__ w2,
    float* __restrict__ U)
{
    const int tid  = threadIdx.x;
    const int lane = tid & 63;
    const int wv   = tid >> 6;
    const int h0   = __builtin_amdgcn_readfirstlane(blockIdx.y*64 + wv*16);
    const int r    = blockIdx.x*64 + lane;          // 0..6335
    const float* pcol = Pt + r;
    const float* wrow = W1 + h0;
    float acc[16] = {};
    float pc = pcol[0];
    #pragma unroll 2
    for (int k = 0; k < T_LEN; ++k) {
        float pn = (k < T_LEN-1) ? pcol[(size_t)(k+1)*SEQ] : 0.f;
        const float* wk = wrow + (size_t)k*NH;
        #pragma unroll
        for (int j = 0; j < 16; ++j) acc[j] = fmaf(pc, wk[j], acc[j]);
        pc = pn;
    }
    #pragma unroll
    for (int j = 0; j < 16; ++j) {
        float th = tanhf(acc[j] + b1[h0+j]);
        acc[j] = (1.f - th*th) * w2[h0+j];
    }
    #pragma unroll
    for (int q = 0; q < 4; ++q) {
        float4 v = make_float4(acc[4*q], acc[4*q+1], acc[4*q+2], acc[4*q+3]);
        *(float4*)&U[(size_t)r*NH + h0 + 4*q] = v;
    }
}

__device__ __forceinline__ float rowval_pt(const float* __restrict__ Pt,
                                           int ii, int bb, int t)
{
    if (ii <= 2)  return Pt[(size_t)t*SEQ + bb];
    if (ii <= 99) return Pt[(size_t)t*SEQ + 64 + (ii-3)*64 + bb];
    return 0.f;
}

// ---------------- Kernel 3: 3000x6400x256 GEMM + fused V-build + epilogue -
// V row n built on the fly: 0.5*(U[ra]+U[rb]) (identical expression to the
// old k_vbuild). rowval reads Pt (k-major). Ascending-k chain bit-identical.
__global__ __launch_bounds__(256) void k_out(
    const float* __restrict__ Pt, const float* __restrict__ W1,
    const float* __restrict__ U, const int* __restrict__ freq_index,
    float* __restrict__ out)
{
    __shared__ float As[KCO*LDA];   // [k][t]
    __shared__ float Vs[KCO*LDA];   // [k][n]
    __shared__ int  inv[NI];
    const int tid = threadIdx.x;
    const int tb  = blockIdx.x;     // 0..23
    const int nb  = blockIdx.y;     // 0..49
    if (tid < NI) inv[freq_index[tid]] = tid;

    const int tg = tid & 15;
    const int ig = tid >> 4;
    const int t0 = tb*128, n0 = nb*128;
    const int sk = tid & 7;
    const int sr = tid >> 3;

    int ra[4], rb[4];
    #pragma unroll
    for (int m = 0; m < 4; ++m) {
        int n  = n0 + sr + 32*m;
        int bb = n / 100;
        int ii = n - bb*100;
        ra[m] = (ii <= 2) ? bb : 64 + (ii-3)*64 + bb;
        rb[m] = (ii+1 <= 2) ? bb : ((ii+1 <= 99) ? 64 + (ii-2)*64 + bb : 6336);
    }

    float acc[8][8] = {};

    for (int c = 0; c < 8; ++c) {
        const int k0 = c*KCO;
        __syncthreads();
        #pragma unroll
        for (int m = 0; m < 4; ++m) {
            int row = sr + 32*m;
            int tg_ = t0 + row; if (tg_ > T_LEN-1) tg_ = T_LEN-1;
            float4 a = *(const float4*)(W1 + (size_t)tg_*NH + k0 + sk*4);
            As[(sk*4+0)*LDA + row] = a.x;
            As[(sk*4+1)*LDA + row] = a.y;
            As[(sk*4+2)*LDA + row] = a.z;
            As[(sk*4+3)*LDA + row] = a.w;
            float4 ua = *(const float4*)(U + (size_t)ra[m]*NH + k0 + sk*4);
            float4 ub = *(const float4*)(U + (size_t)rb[m]*NH + k0 + sk*4);
            Vs[(sk*4+0)*LDA + row] = 0.5f*(ua.x + ub.x);
            Vs[(sk*4+1)*LDA + row] = 0.5f*(ua.y + ub.y);
            Vs[(sk*4+2)*LDA + row] = 0.5f*(ua.z + ub.z);
            Vs[(sk*4+3)*LDA + row] = 0.5f*(ua.w + ub.w);
        }
        __syncthreads();
        #pragma unroll 4
        for (int k = 0; k < KCO; ++k) {
            float4 alo = *(const float4*)&As[k*LDA + tg*8];
            float4 ahi = *(const float4*)&As[k*LDA + tg*8 + 4];
            float4 vlo = *(const float4*)&Vs[k*LDA + ig*8];
            float4 vhi = *(const float4*)&Vs[k*LDA + ig*8 + 4];
            float a[8] = {alo.x, alo.y, alo.z, alo.w, ahi.x, ahi.y, ahi.z, ahi.w};
            float v[8] = {vlo.x, vlo.y, vlo.z, vlo.w, vhi.x, vhi.y, vhi.z, vhi.w};
            #pragma unroll
            for (int mt = 0; mt < 8; ++mt)
                #pragma unroll
                for (int nn = 0; nn < 8; ++nn)
                    acc[mt][nn] = fmaf(a[mt], v[nn], acc[mt][nn]);
        }
    }

    #pragma unroll
    for (int mt = 0; mt < 8; ++mt) {
        const int t = t0 + tg*8 + mt;
        if (t < T_LEN) {
            float rv = 0.f;
            #pragma unroll
            for (int nn = 0; nn < 8; ++nn) {
                const int n  = n0 + ig*8 + nn;
                const int bb = n / 100;
                const int ii = n - bb*100;
                if (nn == 0 || ii == 0) rv = rowval_pt(Pt, ii, bb, t);
                float rvn = rowval_pt(Pt, ii+1, bb, t);
                out[(size_t)bb*T_LEN*NI + (size_t)t*NI + inv[ii]]
                    = acc[mt][nn] * (rv - rvn);
                rv = rvn;
            }
        }
    }
}

extern "C" void kernel_launch(void* const* d_in, const int* in_sizes, int n_in,
                              void* d_out, int out_size, void* d_ws, size_t ws_size,
                              hipStream_t stream) {
    const float* x      = (const float*)d_in[0];
    const float* b_all  = (const float*)d_in[1];
    const float* a_all  = (const float*)d_in[2];
    const float* zi_all = (const float*)d_in[3];
    const float* W1     = (const float*)d_in[4];
    const float* b1     = (const float*)d_in[5];
    const float* w2     = (const float*)d_in[6];
    const int*   fidx   = (const int*)d_in[7];
    float* out = (float*)d_out;

    float* Pt = (float*)d_ws;                       // [3000][6336] k-major
    float* U  = Pt + (size_t)T_LEN * SEQ;           // [6337][256] (+pseudo row)
    // total workspace: 82.5 MB (< proven 88.3 MB)

    hipLaunchKernelGGL(k_prep, dim3((T_LEN+63)/64), dim3(256), 0, stream,
                       x, b1, w2, Pt, U);
    hipLaunchKernelGGL(k_filtfilt, dim3(NF), dim3(64), 0, stream,
                       Pt, b_all, a_all, zi_all);
    hipLaunchKernelGGL(k_ugemm, dim3(SEQ/64, 4), dim3(256), 0, stream,
                       Pt, W1, b1, w2, U);
    hipLaunchKernelGGL(k_out, dim3((T_LEN+127)/128, (NB*NI)/128), dim3(256), 0, stream,
                       Pt, W1, U, fidx, out);
}

// Round 11
// 680.157 us; speedup vs baseline: 1.5978x; 1.5978x over previous
//
#include <hip/hip_runtime.h>
#include <math.h>

#define T_LEN 3000
#define EDGE 15
#define NF 97
#define NB 64
#define NH 256
#define NI 100
#define SEQ 6336       // Pt row width: 64 x-cols + 6208 filter cols
#define KCO 32         // k_out K-chunk: 256 = 8*32
#define LDA 132        // k_out LDS row stride (floats)
#define KS 8           // k_ugemm split-K factor
#define KPB 375        // k per block = 3000/KS
#define KC2 25         // k_ugemm LDS k-chunk (375 = 15*25)
#define LDB 132        // k_ugemm LDS row stride (floats)
#define UPROWS 6400    // padded partial rows (50 tiles * 128)

// ---------------- Kernel 0: k_prep — x^T into Pt cols 0..63 + pseudo U row
__global__ __launch_bounds__(256) void k_prep(
    const float* __restrict__ x, const float* __restrict__ b1,
    const float* __restrict__ w2, float* __restrict__ Pt, float* __restrict__ U)
{
    const int kk0 = blockIdx.x * 64;
    const int b   = threadIdx.x & 63;
    const int ko  = threadIdx.x >> 6;     // 0..3
    #pragma unroll
    for (int p = 0; p < 16; ++p) {
        int kk = kk0 + ko + 4*p;
        if (kk < T_LEN) Pt[(size_t)kk*SEQ + b] = x[(size_t)b*T_LEN + kk];
    }
    if (blockIdx.x == 0) {
        int h = threadIdx.x;              // 256 threads = 256 h
        float th = tanhf(b1[h]);
        U[(size_t)SEQ*NH + h] = (1.f - th*th) * w2[h];
    }
}

// ---------------- Kernel 1: filtfilt on Pt (k-major, fully coalesced) -----
__global__ __launch_bounds__(64) void k_filtfilt(
    float* Pt, const float* __restrict__ b_all,
    const float* __restrict__ a_all, const float* __restrict__ zi_all)
{
    const int f    = blockIdx.x;
    const int lane = threadIdx.x;
    const double bc0 = b_all[f*5+0], bc1 = b_all[f*5+1], bc2 = b_all[f*5+2],
                 bc3 = b_all[f*5+3], bc4 = b_all[f*5+4];
    const double ac1 = a_all[f*5+1], ac2 = a_all[f*5+2],
                 ac3 = a_all[f*5+3], ac4 = a_all[f*5+4];
    const double zi0 = zi_all[f*4+0], zi1 = zi_all[f*4+1],
                 zi2 = zi_all[f*4+2], zi3 = zi_all[f*4+3];
    const float* xc = Pt + lane;                       // x column
    float*       yc = Pt + 64 + (size_t)f*64 + lane;   // y column

    double z0, z1, z2, z3;

#define FSTEP(XV, DST) { double xv = (XV); \
    double yv = fma(bc0, xv, z0); \
    z0 = fma(bc1, xv, z1) - ac1*yv; \
    z1 = fma(bc2, xv, z2) - ac2*yv; \
    z2 = fma(bc3, xv, z3) - ac3*yv; \
    z3 = bc4*xv - ac4*yv; \
    DST = (float)yv; }

    const double x0 = (double)xc[0];
    const double xl = (double)xc[(size_t)(T_LEN-1)*SEQ];
    { const double e0 = 2.0*x0 - (double)xc[(size_t)EDGE*SEQ];
      z0 = zi0*e0; z1 = zi1*e0; z2 = zi2*e0; z3 = zi3*e0; }

    // left edge (15 steps, state only — outputs never used)
    {
        float le[15];
        #pragma unroll
        for (int i = 0; i < 15; ++i) le[i] = xc[(size_t)(EDGE - i)*SEQ];
        #pragma unroll
        for (int i = 0; i < 15; ++i) { float o; FSTEP(2.0*x0 - (double)le[i], o); (void)o; }
    }
    // main fwd
    {
        float cur[20], nxt[20];
        #pragma unroll
        for (int j = 0; j < 20; ++j) cur[j] = xc[(size_t)j*SEQ];
        for (int kk = 0; kk < T_LEN; kk += 20) {
            if (kk + 20 < T_LEN) {
                #pragma unroll
                for (int j = 0; j < 20; ++j) nxt[j] = xc[(size_t)(kk+20+j)*SEQ];
            }
            #pragma unroll
            for (int j = 0; j < 20; ++j) {
                float o; FSTEP((double)cur[j], o); yc[(size_t)(kk+j)*SEQ] = o;
            }
            #pragma unroll
            for (int j = 0; j < 20; ++j) cur[j] = nxt[j];
        }
    }
    // right edge (ext i = 3015..3029): y kept in regs
    float yr[15];
    {
        float re[15];
        #pragma unroll
        for (int i = 0; i < 15; ++i) re[i] = xc[(size_t)(T_LEN-2-i)*SEQ];
        #pragma unroll
        for (int i = 0; i < 15; ++i) { float o; FSTEP(2.0*xl - (double)re[i], o); yr[i] = o; }
    }

    // backward pass (descending ext i), in place on yc
    const double yl = (double)yr[14];
    z0 = zi0*yl; z1 = zi1*yl; z2 = zi2*yl; z3 = zi3*yl;
    #pragma unroll
    for (int i = 14; i >= 0; --i) { float o; FSTEP((double)yr[i], o); (void)o; }
    {
        float bcur[20], bnxt[20];
        #pragma unroll
        for (int j = 0; j < 20; ++j) bcur[j] = yc[(size_t)(2980+j)*SEQ];
        for (int kt = 2980; kt >= 0; kt -= 20) {
            if (kt >= 20) {
                #pragma unroll
                for (int j = 0; j < 20; ++j) bnxt[j] = yc[(size_t)(kt-20+j)*SEQ];
            }
            #pragma unroll
            for (int j = 19; j >= 0; --j) { float o; FSTEP((double)bcur[j], o); bcur[j] = o; }
            #pragma unroll
            for (int j = 0; j < 20; ++j) yc[(size_t)(kt+j)*SEQ] = bcur[j];
            #pragma unroll
            for (int j = 0; j < 20; ++j) bcur[j] = bnxt[j];
        }
    }
#undef FSTEP
}

// ---------------- Kernel 2a: split-K GEMM partials -------------------------
// Up[ks][r][h] = sum_{k in ks-th 375-slice, ascending} Pt[k][r] * W1[k][h].
// 128r x 128h tile, 256 thr, 8x8 thread tile. Both operands k-major in
// memory -> staging is pure coalesced float4 copy (no transpose).
// Grid 50 x 2 x 8 = 800 blocks. Partials live in d_out (overwritten later).
__global__ __launch_bounds__(256) void k_ugemm(
    const float* __restrict__ Pt, const float* __restrict__ W1,
    float* __restrict__ Up)
{
    __shared__ float As[KC2*LDB];   // [k][128 r]
    __shared__ float Bs[KC2*LDB];   // [k][128 h]
    const int tid = threadIdx.x;
    const int rq = blockIdx.x;      // 0..49
    const int hq = blockIdx.y;      // 0..1
    const int ks = blockIdx.z;      // 0..7
    const int r0 = rq*128, h0 = hq*128;
    const int tg = tid & 15, ig = tid >> 4;

    float acc[8][8] = {};

    for (int c = 0; c < KPB/KC2; ++c) {          // 15 chunks of 25 k
        const int k0 = ks*KPB + c*KC2;
        __syncthreads();
        for (int q = tid; q < KC2*32; q += 256) {    // 800 float4s per tile
            const int kq = q >> 5;                   // 0..24
            const int r4 = (q & 31) << 2;            // 0..124
            const float* psrc = Pt + (size_t)(k0+kq)*SEQ;
            float4 a;
            if (r0 + r4 + 3 < SEQ) a = *(const float4*)(psrc + r0 + r4);
            else {                                    // tail tile: clamp (rows discarded)
                a.x = psrc[min(r0+r4+0, SEQ-1)];
                a.y = psrc[min(r0+r4+1, SEQ-1)];
                a.z = psrc[min(r0+r4+2, SEQ-1)];
                a.w = psrc[min(r0+r4+3, SEQ-1)];
            }
            *(float4*)&As[kq*LDB + r4] = a;
            float4 b = *(const float4*)(W1 + (size_t)(k0+kq)*NH + h0 + r4);
            *(float4*)&Bs[kq*LDB + r4] = b;
        }
        __syncthreads();
        #pragma unroll 5
        for (int k = 0; k < KC2; ++k) {
            float4 alo = *(const float4*)&As[k*LDB + tg*8];
            float4 ahi = *(const float4*)&As[k*LDB + tg*8 + 4];
            float4 blo = *(const float4*)&Bs[k*LDB + ig*8];
            float4 bhi = *(const float4*)&Bs[k*LDB + ig*8 + 4];
            float a[8] = {alo.x,alo.y,alo.z,alo.w,ahi.x,ahi.y,ahi.z,ahi.w};
            float b[8] = {blo.x,blo.y,blo.z,blo.w,bhi.x,bhi.y,bhi.z,bhi.w};
            #pragma unroll
            for (int mt = 0; mt < 8; ++mt)
                #pragma unroll
                for (int nn = 0; nn < 8; ++nn)
                    acc[mt][nn] = fmaf(a[mt], b[nn], acc[mt][nn]);
        }
    }

    float* up = Up + (size_t)ks*UPROWS*NH;
    #pragma unroll
    for (int mt = 0; mt < 8; ++mt) {
        const int r = r0 + tg*8 + mt;
        if (r < SEQ) {
            *(float4*)&up[(size_t)r*NH + h0 + ig*8]
                = make_float4(acc[mt][0], acc[mt][1], acc[mt][2], acc[mt][3]);
            *(float4*)&up[(size_t)r*NH + h0 + ig*8 + 4]
                = make_float4(acc[mt][4], acc[mt][5], acc[mt][6], acc[mt][7]);
        }
    }
}

// ---------------- Kernel 2b: reduce partials (fixed ks-ascending order) ----
__global__ __launch_bounds__(256) void k_ured(
    const float* __restrict__ Up, const float* __restrict__ b1,
    const float* __restrict__ w2, float* __restrict__ U)
{
    const int e = blockIdx.x*256 + threadIdx.x;   // 0..405503
    const int r = e >> 6;
    const int h = (e & 63) << 2;
    float4 s = *(const float4*)(Up + (size_t)r*NH + h);
    #pragma unroll
    for (int ks = 1; ks < KS; ++ks) {
        float4 t = *(const float4*)(Up + (size_t)ks*UPROWS*NH + (size_t)r*NH + h);
        s.x += t.x; s.y += t.y; s.z += t.z; s.w += t.w;
    }
    float4 bv = *(const float4*)(b1 + h);
    float4 wv = *(const float4*)(w2 + h);
    float t0 = tanhf(s.x + bv.x), t1 = tanhf(s.y + bv.y),
          t2 = tanhf(s.z + bv.z), t3 = tanhf(s.w + bv.w);
    *(float4*)&U[(size_t)r*NH + h]
        = make_float4((1.f - t0*t0)*wv.x, (1.f - t1*t1)*wv.y,
                      (1.f - t2*t2)*wv.z, (1.f - t3*t3)*wv.w);
}

__device__ __forceinline__ float rowval_pt(const float* __restrict__ Pt,
                                           int ii, int bb, int t)
{
    if (ii <= 2)  return Pt[(size_t)t*SEQ + bb];
    if (ii <= 99) return Pt[(size_t)t*SEQ + 64 + (ii-3)*64 + bb];
    return 0.f;
}

// ---------------- Kernel 3: 3000x6400x256 GEMM + fused V-build + epilogue -
__global__ __launch_bounds__(256) void k_out(
    const float* __restrict__ Pt, const float* __restrict__ W1,
    const float* __restrict__ U, const int* __restrict__ freq_index,
    float* __restrict__ out)
{
    __shared__ float As[KCO*LDA];   // [k][t]
    __shared__ float Vs[KCO*LDA];   // [k][n]
    __shared__ int  inv[NI];
    const int tid = threadIdx.x;
    const int tb  = blockIdx.x;     // 0..23
    const int nb  = blockIdx.y;     // 0..49
    if (tid < NI) inv[freq_index[tid]] = tid;

    const int tg = tid & 15;
    const int ig = tid >> 4;
    const int t0 = tb*128, n0 = nb*128;
    const int sk = tid & 7;
    const int sr = tid >> 3;

    int ra[4], rb[4];
    #pragma unroll
    for (int m = 0; m < 4; ++m) {
        int n  = n0 + sr + 32*m;
        int bb = n / 100;
        int ii = n - bb*100;
        ra[m] = (ii <= 2) ? bb : 64 + (ii-3)*64 + bb;
        rb[m] = (ii+1 <= 2) ? bb : ((ii+1 <= 99) ? 64 + (ii-2)*64 + bb : SEQ);
    }

    float acc[8][8] = {};

    for (int c = 0; c < 8; ++c) {
        const int k0 = c*KCO;
        __syncthreads();
        #pragma unroll
        for (int m = 0; m < 4; ++m) {
            int row = sr + 32*m;
            int tg_ = t0 + row; if (tg_ > T_LEN-1) tg_ = T_LEN-1;
            float4 a = *(const float4*)(W1 + (size_t)tg_*NH + k0 + sk*4);
            As[(sk*4+0)*LDA + row] = a.x;
            As[(sk*4+1)*LDA + row] = a.y;
            As[(sk*4+2)*LDA + row] = a.z;
            As[(sk*4+3)*LDA + row] = a.w;
            float4 ua = *(const float4*)(U + (size_t)ra[m]*NH + k0 + sk*4);
            float4 ub = *(const float4*)(U + (size_t)rb[m]*NH + k0 + sk*4);
            Vs[(sk*4+0)*LDA + row] = 0.5f*(ua.x + ub.x);
            Vs[(sk*4+1)*LDA + row] = 0.5f*(ua.y + ub.y);
            Vs[(sk*4+2)*LDA + row] = 0.5f*(ua.z + ub.z);
            Vs[(sk*4+3)*LDA + row] = 0.5f*(ua.w + ub.w);
        }
        __syncthreads();
        #pragma unroll 4
        for (int k = 0; k < KCO; ++k) {
            float4 alo = *(const float4*)&As[k*LDA + tg*8];
            float4 ahi = *(const float4*)&As[k*LDA + tg*8 + 4];
            float4 vlo = *(const float4*)&Vs[k*LDA + ig*8];
            float4 vhi = *(const float4*)&Vs[k*LDA + ig*8 + 4];
            float a[8] = {alo.x, alo.y, alo.z, alo.w, ahi.x, ahi.y, ahi.z, ahi.w};
            float v[8] = {vlo.x, vlo.y, vlo.z, vlo.w, vhi.x, vhi.y, vhi.z, vhi.w};
            #pragma unroll
            for (int mt = 0; mt < 8; ++mt)
                #pragma unroll
                for (int nn = 0; nn < 8; ++nn)
                    acc[mt][nn] = fmaf(a[mt], v[nn], acc[mt][nn]);
        }
    }

    #pragma unroll
    for (int mt = 0; mt < 8; ++mt) {
        const int t = t0 + tg*8 + mt;
        if (t < T_LEN) {
            float rv = 0.f;
            #pragma unroll
            for (int nn = 0; nn < 8; ++nn) {
                const int n  = n0 + ig*8 + nn;
                const int bb = n / 100;
                const int ii = n - bb*100;
                if (nn == 0 || ii == 0) rv = rowval_pt(Pt, ii, bb, t);
                float rvn = rowval_pt(Pt, ii+1, bb, t);
                out[(size_t)bb*T_LEN*NI + (size_t)t*NI + inv[ii]]
                    = acc[mt][nn] * (rv - rvn);
                rv = rvn;
            }
        }
    }
}

extern "C" void kernel_launch(void* const* d_in, const int* in_sizes, int n_in,
                              void* d_out, int out_size, void* d_ws, size_t ws_size,
                              hipStream_t stream) {
    const float* x      = (const float*)d_in[0];
    const float* b_all  = (const float*)d_in[1];
    const float* a_all  = (const float*)d_in[2];
    const float* zi_all = (const float*)d_in[3];
    const float* W1     = (const float*)d_in[4];
    const float* b1     = (const float*)d_in[5];
    const float* w2     = (const float*)d_in[6];
    const int*   fidx   = (const int*)d_in[7];
    float* out = (float*)d_out;

    float* Pt = (float*)d_ws;                       // [3000][6336] k-major
    float* U  = Pt + (size_t)T_LEN * SEQ;           // [6337][256] (+pseudo row)
    float* Up = out;                                // split-K partials (52 MB),
                                                    // consumed by k_ured, then
                                                    // d_out fully rewritten by k_out

    hipLaunchKernelGGL(k_prep, dim3((T_LEN+63)/64), dim3(256), 0, stream,
                       x, b1, w2, Pt, U);
    hipLaunchKernelGGL(k_filtfilt, dim3(NF), dim3(64), 0, stream,
                       Pt, b_all, a_all, zi_all);
    hipLaunchKernelGGL(k_ugemm, dim3(50, 2, KS), dim3(256), 0, stream,
                       Pt, W1, Up);
    hipLaunchKernelGGL(k_ured, dim3(SEQ*64/256), dim3(256), 0, stream,
                       Up, b1, w2, U);
    hipLaunchKernelGGL(k_out, dim3((T_LEN+127)/128, (NB*NI)/128), dim3(256), 0, stream,
                       Pt, W1, U, fidx, out);
}

// Round 12
// 632.873 us; speedup vs baseline: 1.7171x; 1.0747x over previous
//
#include <hip/hip_runtime.h>
#include <math.h>

#define T_LEN 3000
#define EDGE 15
#define NF 97
#define NB 64
#define NH 256
#define NI 100
#define SEQ 6336       // Pt row width: 64 x-cols + 6208 filter cols
#define KCO 32         // k_out K-chunk: 256 = 8*32
#define LDA 132        // k_out LDS row stride (floats)
#define KS 8           // k_ugemm split-K factor
#define KPB 375        // k per block = 3000/KS
#define KC2 25         // k_ugemm LDS k-chunk (375 = 15*25)
#define LDB 132        // k_ugemm LDS row stride (floats)
#define UPROWS 6400    // padded partial rows (50 tiles * 128)

// ---------------- Kernel 0: k_prep — x^T into Pt cols 0..63 + pseudo U row
__global__ __launch_bounds__(256) void k_prep(
    const float* __restrict__ x, const float* __restrict__ b1,
    const float* __restrict__ w2, float* __restrict__ Pt, float* __restrict__ U)
{
    const int kk0 = blockIdx.x * 64;
    const int b   = threadIdx.x & 63;
    const int ko  = threadIdx.x >> 6;     // 0..3
    #pragma unroll
    for (int p = 0; p < 16; ++p) {
        int kk = kk0 + ko + 4*p;
        if (kk < T_LEN) Pt[(size_t)kk*SEQ + b] = x[(size_t)b*T_LEN + kk];
    }
    if (blockIdx.x == 0) {
        int h = threadIdx.x;              // 256 threads = 256 h
        float th = tanhf(b1[h]);
        U[(size_t)SEQ*NH + h] = (1.f - th*th) * w2[h];
    }
}

// ---------------- Kernel 1: filtfilt on Pt (k-major, fully coalesced) -----
// 3-deep software pipeline (A/B/C chunk rotation, 2 chunks of loads always
// in flight ~= 640 cyc cover vs ~500 cyc L3 latency). FSTEP chain identical
// to prior rounds => bit-identical output.
__global__ __launch_bounds__(64) void k_filtfilt(
    float* Pt, const float* __restrict__ b_all,
    const float* __restrict__ a_all, const float* __restrict__ zi_all)
{
    const int f    = blockIdx.x;
    const int lane = threadIdx.x;
    const double bc0 = b_all[f*5+0], bc1 = b_all[f*5+1], bc2 = b_all[f*5+2],
                 bc3 = b_all[f*5+3], bc4 = b_all[f*5+4];
    const double ac1 = a_all[f*5+1], ac2 = a_all[f*5+2],
                 ac3 = a_all[f*5+3], ac4 = a_all[f*5+4];
    const double zi0 = zi_all[f*4+0], zi1 = zi_all[f*4+1],
                 zi2 = zi_all[f*4+2], zi3 = zi_all[f*4+3];
    const float* xc = Pt + lane;                       // x column
    float*       yc = Pt + 64 + (size_t)f*64 + lane;   // y column

    double z0, z1, z2, z3;

#define FSTEP(XV, DST) { double xv = (XV); \
    double yv = fma(bc0, xv, z0); \
    z0 = fma(bc1, xv, z1) - ac1*yv; \
    z1 = fma(bc2, xv, z2) - ac2*yv; \
    z2 = fma(bc3, xv, z3) - ac3*yv; \
    z3 = bc4*xv - ac4*yv; \
    DST = (float)yv; }

    const double x0 = (double)xc[0];
    const double xl = (double)xc[(size_t)(T_LEN-1)*SEQ];
    { const double e0 = 2.0*x0 - (double)xc[(size_t)EDGE*SEQ];
      z0 = zi0*e0; z1 = zi1*e0; z2 = zi2*e0; z3 = zi3*e0; }

    // left edge (15 steps, state only — outputs never used)
    {
        float le[15];
        #pragma unroll
        for (int i = 0; i < 15; ++i) le[i] = xc[(size_t)(EDGE - i)*SEQ];
        #pragma unroll
        for (int i = 0; i < 15; ++i) { float o; FSTEP(2.0*x0 - (double)le[i], o); (void)o; }
    }

#define FLD(BUF, C) { _Pragma("unroll") \
    for (int j = 0; j < 20; ++j) BUF[j] = xc[(size_t)((C)*20 + j)*SEQ]; }
#define FCH(BUF, C) { _Pragma("unroll") \
    for (int j = 0; j < 20; ++j) { float o; FSTEP((double)BUF[j], o); \
        yc[(size_t)((C)*20 + j)*SEQ] = o; } }

    // main fwd: 150 chunks of 20, 3-deep pipeline
    {
        float A[20], B[20], C[20];
        FLD(A, 0); FLD(B, 1); FLD(C, 2);
        for (int g = 0; g < 150; g += 3) {
            FCH(A, g);   if (g + 3 < 150) FLD(A, g+3);
            FCH(B, g+1); if (g + 4 < 150) FLD(B, g+4);
            FCH(C, g+2); if (g + 5 < 150) FLD(C, g+5);
        }
    }
#undef FLD
#undef FCH

    // right edge (ext i = 3015..3029): y kept in regs
    float yr[15];
    {
        float re[15];
        #pragma unroll
        for (int i = 0; i < 15; ++i) re[i] = xc[(size_t)(T_LEN-2-i)*SEQ];
        #pragma unroll
        for (int i = 0; i < 15; ++i) { float o; FSTEP(2.0*xl - (double)re[i], o); yr[i] = o; }
    }

    // backward pass (descending ext i), in place on yc
    const double yl = (double)yr[14];
    z0 = zi0*yl; z1 = zi1*yl; z2 = zi2*yl; z3 = zi3*yl;
    #pragma unroll
    for (int i = 14; i >= 0; --i) { float o; FSTEP((double)yr[i], o); (void)o; }

#define BLD(BUF, C) { _Pragma("unroll") \
    for (int j = 0; j < 20; ++j) BUF[j] = yc[(size_t)((C)*20 + j)*SEQ]; }
#define BCH(BUF, C) { _Pragma("unroll") \
    for (int j = 19; j >= 0; --j) { float o; FSTEP((double)BUF[j], o); BUF[j] = o; } \
    _Pragma("unroll") \
    for (int j = 0; j < 20; ++j) yc[(size_t)((C)*20 + j)*SEQ] = BUF[j]; }

    // 150 chunks descending (chunk c covers kk = c*20 .. c*20+19)
    {
        float A[20], B[20], C[20];
        BLD(A, 149); BLD(B, 148); BLD(C, 147);
        for (int g = 149; g >= 2; g -= 3) {
            BCH(A, g);   if (g - 3 >= 0) BLD(A, g-3);
            BCH(B, g-1); if (g - 4 >= 0) BLD(B, g-4);
            BCH(C, g-2); if (g - 5 >= 0) BLD(C, g-5);
        }
    }
#undef BLD
#undef BCH
#undef FSTEP
}

// ---------------- Kernel 2a: split-K GEMM partials -------------------------
__global__ __launch_bounds__(256) void k_ugemm(
    const float* __restrict__ Pt, const float* __restrict__ W1,
    float* __restrict__ Up)
{
    __shared__ float As[KC2*LDB];   // [k][128 r]
    __shared__ float Bs[KC2*LDB];   // [k][128 h]
    const int tid = threadIdx.x;
    const int rq = blockIdx.x;      // 0..49
    const int hq = blockIdx.y;      // 0..1
    const int ks = blockIdx.z;      // 0..7
    const int r0 = rq*128, h0 = hq*128;
    const int tg = tid & 15, ig = tid >> 4;

    float acc[8][8] = {};

    for (int c = 0; c < KPB/KC2; ++c) {          // 15 chunks of 25 k
        const int k0 = ks*KPB + c*KC2;
        __syncthreads();
        for (int q = tid; q < KC2*32; q += 256) {    // 800 float4s per tile
            const int kq = q >> 5;                   // 0..24
            const int r4 = (q & 31) << 2;            // 0..124
            const float* psrc = Pt + (size_t)(k0+kq)*SEQ;
            float4 a;
            if (r0 + r4 + 3 < SEQ) a = *(const float4*)(psrc + r0 + r4);
            else {                                    // tail tile: clamp (rows discarded)
                a.x = psrc[min(r0+r4+0, SEQ-1)];
                a.y = psrc[min(r0+r4+1, SEQ-1)];
                a.z = psrc[min(r0+r4+2, SEQ-1)];
                a.w = psrc[min(r0+r4+3, SEQ-1)];
            }
            *(float4*)&As[kq*LDB + r4] = a;
            float4 b = *(const float4*)(W1 + (size_t)(k0+kq)*NH + h0 + r4);
            *(float4*)&Bs[kq*LDB + r4] = b;
        }
        __syncthreads();
        #pragma unroll 5
        for (int k = 0; k < KC2; ++k) {
            float4 alo = *(const float4*)&As[k*LDB + tg*8];
            float4 ahi = *(const float4*)&As[k*LDB + tg*8 + 4];
            float4 blo = *(const float4*)&Bs[k*LDB + ig*8];
            float4 bhi = *(const float4*)&Bs[k*LDB + ig*8 + 4];
            float a[8] = {alo.x,alo.y,alo.z,alo.w,ahi.x,ahi.y,ahi.z,ahi.w};
            float b[8] = {blo.x,blo.y,blo.z,blo.w,bhi.x,bhi.y,bhi.z,bhi.w};
            #pragma unroll
            for (int mt = 0; mt < 8; ++mt)
                #pragma unroll
                for (int nn = 0; nn < 8; ++nn)
                    acc[mt][nn] = fmaf(a[mt], b[nn], acc[mt][nn]);
        }
    }

    float* up = Up + (size_t)ks*UPROWS*NH;
    #pragma unroll
    for (int mt = 0; mt < 8; ++mt) {
        const int r = r0 + tg*8 + mt;
        if (r < SEQ) {
            *(float4*)&up[(size_t)r*NH + h0 + ig*8]
                = make_float4(acc[mt][0], acc[mt][1], acc[mt][2], acc[mt][3]);
            *(float4*)&up[(size_t)r*NH + h0 + ig*8 + 4]
                = make_float4(acc[mt][4], acc[mt][5], acc[mt][6], acc[mt][7]);
        }
    }
}

// ---------------- Kernel 2b: reduce partials (fixed ks-ascending order) ----
__global__ __launch_bounds__(256) void k_ured(
    const float* __restrict__ Up, const float* __restrict__ b1,
    const float* __restrict__ w2, float* __restrict__ U)
{
    const int e = blockIdx.x*256 + threadIdx.x;   // 0..405503
    const int r = e >> 6;
    const int h = (e & 63) << 2;
    float4 s = *(const float4*)(Up + (size_t)r*NH + h);
    #pragma unroll
    for (int ks = 1; ks < KS; ++ks) {
        float4 t = *(const float4*)(Up + (size_t)ks*UPROWS*NH + (size_t)r*NH + h);
        s.x += t.x; s.y += t.y; s.z += t.z; s.w += t.w;
    }
    float4 bv = *(const float4*)(b1 + h);
    float4 wv = *(const float4*)(w2 + h);
    float t0 = tanhf(s.x + bv.x), t1 = tanhf(s.y + bv.y),
          t2 = tanhf(s.z + bv.z), t3 = tanhf(s.w + bv.w);
    *(float4*)&U[(size_t)r*NH + h]
        = make_float4((1.f - t0*t0)*wv.x, (1.f - t1*t1)*wv.y,
                      (1.f - t2*t2)*wv.z, (1.f - t3*t3)*wv.w);
}

__device__ __forceinline__ float rowval_pt(const float* __restrict__ Pt,
                                           int ii, int bb, int t)
{
    if (ii <= 2)  return Pt[(size_t)t*SEQ + bb];
    if (ii <= 99) return Pt[(size_t)t*SEQ + 64 + (ii-3)*64 + bb];
    return 0.f;
}

// ---------------- Kernel 3: 3000x6400x256 GEMM + fused V-build + epilogue -
__global__ __launch_bounds__(256) void k_out(
    const float* __restrict__ Pt, const float* __restrict__ W1,
    const float* __restrict__ U, const int* __restrict__ freq_index,
    float* __restrict__ out)
{
    __shared__ float As[KCO*LDA];   // [k][t]
    __shared__ float Vs[KCO*LDA];   // [k][n]
    __shared__ int  inv[NI];
    const int tid = threadIdx.x;
    const int tb  = blockIdx.x;     // 0..23
    const int nb  = blockIdx.y;     // 0..49
    if (tid < NI) inv[freq_index[tid]] = tid;

    const int tg = tid & 15;
    const int ig = tid >> 4;
    const int t0 = tb*128, n0 = nb*128;
    const int sk = tid & 7;
    const int sr = tid >> 3;

    int ra[4], rb[4];
    #pragma unroll
    for (int m = 0; m < 4; ++m) {
        int n  = n0 + sr + 32*m;
        int bb = n / 100;
        int ii = n - bb*100;
        ra[m] = (ii <= 2) ? bb : 64 + (ii-3)*64 + bb;
        rb[m] = (ii+1 <= 2) ? bb : ((ii+1 <= 99) ? 64 + (ii-2)*64 + bb : SEQ);
    }

    float acc[8][8] = {};

    for (int c = 0; c < 8; ++c) {
        const int k0 = c*KCO;
        __syncthreads();
        #pragma unroll
        for (int m = 0; m < 4; ++m) {
            int row = sr + 32*m;
            int tg_ = t0 + row; if (tg_ > T_LEN-1) tg_ = T_LEN-1;
            float4 a = *(const float4*)(W1 + (size_t)tg_*NH + k0 + sk*4);
            As[(sk*4+0)*LDA + row] = a.x;
            As[(sk*4+1)*LDA + row] = a.y;
            As[(sk*4+2)*LDA + row] = a.z;
            As[(sk*4+3)*LDA + row] = a.w;
            float4 ua = *(const float4*)(U + (size_t)ra[m]*NH + k0 + sk*4);
            float4 ub = *(const float4*)(U + (size_t)rb[m]*NH + k0 + sk*4);
            Vs[(sk*4+0)*LDA + row] = 0.5f*(ua.x + ub.x);
            Vs[(sk*4+1)*LDA + row] = 0.5f*(ua.y + ub.y);
            Vs[(sk*4+2)*LDA + row] = 0.5f*(ua.z + ub.z);
            Vs[(sk*4+3)*LDA + row] = 0.5f*(ua.w + ub.w);
        }
        __syncthreads();
        #pragma unroll 4
        for (int k = 0; k < KCO; ++k) {
            float4 alo = *(const float4*)&As[k*LDA + tg*8];
            float4 ahi = *(const float4*)&As[k*LDA + tg*8 + 4];
            float4 vlo = *(const float4*)&Vs[k*LDA + ig*8];
            float4 vhi = *(const float4*)&Vs[k*LDA + ig*8 + 4];
            float a[8] = {alo.x, alo.y, alo.z, alo.w, ahi.x, ahi.y, ahi.z, ahi.w};
            float v[8] = {vlo.x, vlo.y, vlo.z, vlo.w, vhi.x, vhi.y, vhi.z, vhi.w};
            #pragma unroll
            for (int mt = 0; mt < 8; ++mt)
                #pragma unroll
                for (int nn = 0; nn < 8; ++nn)
                    acc[mt][nn] = fmaf(a[mt], v[nn], acc[mt][nn]);
        }
    }

    #pragma unroll
    for (int mt = 0; mt < 8; ++mt) {
        const int t = t0 + tg*8 + mt;
        if (t < T_LEN) {
            float rv = 0.f;
            #pragma unroll
            for (int nn = 0; nn < 8; ++nn) {
                const int n  = n0 + ig*8 + nn;
                const int bb = n / 100;
                const int ii = n - bb*100;
                if (nn == 0 || ii == 0) rv = rowval_pt(Pt, ii, bb, t);
                float rvn = rowval_pt(Pt, ii+1, bb, t);
                out[(size_t)bb*T_LEN*NI + (size_t)t*NI + inv[ii]]
                    = acc[mt][nn] * (rv - rvn);
                rv = rvn;
            }
        }
    }
}

extern "C" void kernel_launch(void* const* d_in, const int* in_sizes, int n_in,
                              void* d_out, int out_size, void* d_ws, size_t ws_size,
                              hipStream_t stream) {
    const float* x      = (const float*)d_in[0];
    const float* b_all  = (const float*)d_in[1];
    const float* a_all  = (const float*)d_in[2];
    const float* zi_all = (const float*)d_in[3];
    const float* W1     = (const float*)d_in[4];
    const float* b1     = (const float*)d_in[5];
    const float* w2     = (const float*)d_in[6];
    const int*   fidx   = (const int*)d_in[7];
    float* out = (float*)d_out;

    float* Pt = (float*)d_ws;                       // [3000][6336] k-major
    float* U  = Pt + (size_t)T_LEN * SEQ;           // [6337][256] (+pseudo row)
    float* Up = out;                                // split-K partials (52 MB),
                                                    // consumed by k_ured, then
                                                    // d_out fully rewritten by k_out

    hipLaunchKernelGGL(k_prep, dim3((T_LEN+63)/64), dim3(256), 0, stream,
                       x, b1, w2, Pt, U);
    hipLaunchKernelGGL(k_filtfilt, dim3(NF), dim3(64), 0, stream,
                       Pt, b_all, a_all, zi_all);
    hipLaunchKernelGGL(k_ugemm, dim3(50, 2, KS), dim3(256), 0, stream,
                       Pt, W1, Up);
    hipLaunchKernelGGL(k_ured, dim3(SEQ*64/256), dim3(256), 0, stream,
                       Up, b1, w2, U);
    hipLaunchKernelGGL(k_out, dim3((T_LEN+127)/128, (NB*NI)/128), dim3(256), 0, stream,
                       Pt, W1, U, fidx, out);
}

// Round 13
// 578.144 us; speedup vs baseline: 1.8797x; 1.0947x over previous
//
#include <hip/hip_runtime.h>
#include <math.h>

#define T_LEN 3000
#define NF 97
#define NB 64
#define NH 256
#define NI 100
#define SEQ 6336       // Pt row width: 64 x-cols + 6208 filter cols
#define KCO 32         // k_out K-chunk
#define LDA 132        // k_out LDS row stride
#define KS 8           // k_ugemm split-K factor
#define KPB 375
#define KC2 25
#define LDB 132
#define UPROWS 6400
#define LF 202         // fwd segment length (15*202 = 3030)
#define LB 201         // bwd segment length (15*201 = 3015)
#define NSEG 15

// ---------------- Kernel 0: k_prep — x^T into Pt cols 0..63 + pseudo U row
__global__ __launch_bounds__(256) void k_prep(
    const float* __restrict__ x, const float* __restrict__ b1,
    const float* __restrict__ w2, float* __restrict__ Pt, float* __restrict__ U)
{
    const int kk0 = blockIdx.x * 64;
    const int b   = threadIdx.x & 63;
    const int ko  = threadIdx.x >> 6;
    #pragma unroll
    for (int p = 0; p < 16; ++p) {
        int kk = kk0 + ko + 4*p;
        if (kk < T_LEN) Pt[(size_t)kk*SEQ + b] = x[(size_t)b*T_LEN + kk];
    }
    if (blockIdx.x == 0) {
        int h = threadIdx.x;
        float th = tanhf(b1[h]);
        U[(size_t)SEQ*NH + h] = (1.f - th*th) * w2[h];
    }
}

// ---------------- k_hom: H[f][j][i] = (M^j)[0][i], plus M^LB, M^LF ---------
__global__ __launch_bounds__(64) void k_hom(
    const float* __restrict__ a_all, double* __restrict__ H,
    double* __restrict__ Mbd, double* __restrict__ Mfd)
{
    const int ft = blockIdx.x*64 + threadIdx.x;
    const int f = ft >> 2, ib = ft & 3;
    if (f >= NF) return;
    const double a1 = a_all[f*5+1], a2 = a_all[f*5+2],
                 a3 = a_all[f*5+3], a4 = a_all[f*5+4];
    double z0 = (ib==0), z1 = (ib==1), z2 = (ib==2), z3 = (ib==3);
    for (int j = 0; j <= LF; ++j) {
        if (j < LF) H[((size_t)f*LF + j)*4 + ib] = z0;
        if (j == LB) {
            Mbd[f*16 + 0*4 + ib] = z0; Mbd[f*16 + 1*4 + ib] = z1;
            Mbd[f*16 + 2*4 + ib] = z2; Mbd[f*16 + 3*4 + ib] = z3;
        }
        if (j == LF) {
            Mfd[f*16 + 0*4 + ib] = z0; Mfd[f*16 + 1*4 + ib] = z1;
            Mfd[f*16 + 2*4 + ib] = z2; Mfd[f*16 + 3*4 + ib] = z3;
            break;
        }
        double yv = z0;
        z0 = z1 - a1*yv; z1 = z2 - a2*yv; z2 = z3 - a3*yv; z3 = -a4*yv;
    }
}

#define COEFS \
    const double bc0 = b_all[f*5+0], bc1 = b_all[f*5+1], bc2 = b_all[f*5+2], \
                 bc3 = b_all[f*5+3], bc4 = b_all[f*5+4]; \
    const double ac1 = a_all[f*5+1], ac2 = a_all[f*5+2], \
                 ac3 = a_all[f*5+3], ac4 = a_all[f*5+4];

#define FSTEP(XV, DST) { double xv = (XV); \
    double yv = fma(bc0, xv, z0); \
    z0 = fma(bc1, xv, z1) - ac1*yv; \
    z1 = fma(bc2, xv, z2) - ac2*yv; \
    z2 = fma(bc3, xv, z3) - ac3*yv; \
    z3 = bc4*xv - ac4*yv; \
    DST = (float)yv; }

// ---------------- k_seg_fwd: zero-state forward pass per segment ----------
__global__ __launch_bounds__(64) void k_seg_fwd(
    float* Pt, const float* __restrict__ b_all, const float* __restrict__ a_all,
    const float* __restrict__ zi_all, float* __restrict__ YRb,
    double* __restrict__ Zef)
{
    const int f = blockIdx.x, p = blockIdx.y, b = threadIdx.x;
    COEFS
    const float* xc = Pt + b;
    float* ycol = Pt + 64 + (size_t)f*64 + b;
    double z0 = 0, z1 = 0, z2 = 0, z3 = 0;

    if (p == 0) {
        const double x0 = (double)xc[0];
        const double e0 = 2.0*x0 - (double)xc[(size_t)15*SEQ];
        z0 = (double)zi_all[f*4+0]*e0; z1 = (double)zi_all[f*4+1]*e0;
        z2 = (double)zi_all[f*4+2]*e0; z3 = (double)zi_all[f*4+3]*e0;
        float le[15];
        #pragma unroll
        for (int i = 0; i < 15; ++i) le[i] = xc[(size_t)(15-i)*SEQ];
        #pragma unroll
        for (int i = 0; i < 15; ++i) { float o; FSTEP(2.0*x0 - (double)le[i], o); (void)o; }
    }
    int kk0, n;
    if (p == 0)       { kk0 = 0;          n = 187; }
    else if (p < 14)  { kk0 = p*LF - 15;  n = LF;  }
    else              { kk0 = 2813;       n = 187; }

    {
        const int nc = n/20, rem = n - nc*20;
        float A[20], B[20], C[20];
#define LDF(BUF, c) { _Pragma("unroll") \
        for (int j = 0; j < 20; ++j) BUF[j] = xc[(size_t)(kk0+(c)*20+j)*SEQ]; }
#define CHF(BUF, c) { _Pragma("unroll") \
        for (int j = 0; j < 20; ++j) { float o; FSTEP((double)BUF[j], o); \
            ycol[(size_t)(kk0+(c)*20+j)*SEQ] = o; } }
        if (nc > 0) LDF(A, 0); if (nc > 1) LDF(B, 1); if (nc > 2) LDF(C, 2);
        for (int g = 0; g < nc; g += 3) {
            CHF(A, g); if (g+3 < nc) LDF(A, g+3);
            if (g+1 < nc) { CHF(B, g+1); if (g+4 < nc) LDF(B, g+4); }
            if (g+2 < nc) { CHF(C, g+2); if (g+5 < nc) LDF(C, g+5); }
        }
        if (rem) {
            float T[19];
            #pragma unroll
            for (int j = 0; j < 19; ++j) if (j < rem) T[j] = xc[(size_t)(kk0+nc*20+j)*SEQ];
            #pragma unroll
            for (int j = 0; j < 19; ++j) if (j < rem) {
                float o; FSTEP((double)T[j], o); ycol[(size_t)(kk0+nc*20+j)*SEQ] = o;
            }
        }
#undef LDF
#undef CHF
    }
    if (p == 14) {
        const double xl = (double)xc[(size_t)(T_LEN-1)*SEQ];
        float re[15];
        #pragma unroll
        for (int i = 0; i < 15; ++i) re[i] = xc[(size_t)(2998-i)*SEQ];
        #pragma unroll
        for (int i = 0; i < 15; ++i) {
            float o; FSTEP(2.0*xl - (double)re[i], o);
            YRb[((size_t)f*15 + i)*64 + b] = o;
        }
    }
    double* ze = Zef + (((size_t)f*NSEG + p)*64 + b)*4;
    ze[0] = z0; ze[1] = z1; ze[2] = z2; ze[3] = z3;
}

// ---------------- k_stitch: boundary-state recurrence (generic fwd/bwd) ---
__global__ __launch_bounds__(64) void k_stitch(
    const double* __restrict__ Ze, const double* __restrict__ Mm,
    double* __restrict__ Zo)
{
    const int f = blockIdx.x, b = threadIdx.x;
    double m[16];
    #pragma unroll
    for (int r = 0; r < 16; ++r) m[r] = Mm[f*16 + r];
    const double* z0p = Ze + (((size_t)f*NSEG + 0)*64 + b)*4;
    double z0 = z0p[0], z1 = z0p[1], z2 = z0p[2], z3 = z0p[3];
    {   double* o = Zo + (((size_t)f*NSEG + 1)*64 + b)*4;
        o[0]=z0; o[1]=z1; o[2]=z2; o[3]=z3; }
    for (int p = 1; p <= 13; ++p) {
        const double* zep = Ze + (((size_t)f*NSEG + p)*64 + b)*4;
        double n0 = zep[0] + m[0]*z0  + m[1]*z1  + m[2]*z2  + m[3]*z3;
        double n1 = zep[1] + m[4]*z0  + m[5]*z1  + m[6]*z2  + m[7]*z3;
        double n2 = zep[2] + m[8]*z0  + m[9]*z1  + m[10]*z2 + m[11]*z3;
        double n3 = zep[3] + m[12]*z0 + m[13]*z1 + m[14]*z2 + m[15]*z3;
        z0 = n0; z1 = n1; z2 = n2; z3 = n3;
        double* o = Zo + (((size_t)f*NSEG + p + 1)*64 + b)*4;
        o[0]=z0; o[1]=z1; o[2]=z2; o[3]=z3;
    }
}

// ---------------- k_corr_fwd: y[s] += H[j]·z_init for segments 1..14 ------
__global__ __launch_bounds__(64) void k_corr_fwd(
    float* Pt, float* __restrict__ YRb, const double* __restrict__ H,
    const double* __restrict__ Zf)
{
    const int f = blockIdx.x, p = blockIdx.y + 1, b = threadIdx.x;
    const double* zp = Zf + (((size_t)f*NSEG + p)*64 + b)*4;
    const double w0 = zp[0], w1 = zp[1], w2 = zp[2], w3 = zp[3];
    const double* Hf = H + (size_t)f*LF*4;
    float* ycol = Pt + 64 + (size_t)f*64 + b;
    float* yrp  = YRb + (size_t)f*15*64 + b;
    const int s0 = p*LF;
    #pragma unroll 4
    for (int j = 0; j < LF; ++j) {
        const int s = s0 + j;
        double corr = Hf[j*4+0]*w0 + Hf[j*4+1]*w1 + Hf[j*4+2]*w2 + Hf[j*4+3]*w3;
        if (s < 3015) {
            float* d = &ycol[(size_t)(s-15)*SEQ];
            *d = (float)((double)*d + corr);
        } else {
            float* d = &yrp[(size_t)(s-3015)*64];
            *d = (float)((double)*d + corr);
        }
    }
}

// ---------------- k_seg_bwd: zero-state backward pass per segment ---------
__global__ __launch_bounds__(64) void k_seg_bwd(
    float* Pt, const float* __restrict__ b_all, const float* __restrict__ a_all,
    const float* __restrict__ zi_all, const float* __restrict__ YRb,
    double* __restrict__ Zeb)
{
    const int f = blockIdx.x, p = blockIdx.y, b = threadIdx.x;
    COEFS
    float* ycol = Pt + 64 + (size_t)f*64 + b;
    const float* yrp = YRb + (size_t)f*15*64 + b;
    double z0 = 0, z1 = 0, z2 = 0, z3 = 0;

    if (p == 0) {
        const double yl = (double)yrp[14*64];
        z0 = (double)zi_all[f*4+0]*yl; z1 = (double)zi_all[f*4+1]*yl;
        z2 = (double)zi_all[f*4+2]*yl; z3 = (double)zi_all[f*4+3]*yl;
        float t15[15];
        #pragma unroll
        for (int i = 0; i < 15; ++i) t15[i] = yrp[(size_t)(14-i)*64];
        #pragma unroll
        for (int i = 0; i < 15; ++i) { float o; FSTEP((double)t15[i], o); (void)o; }
    }
    int kkH, n;
    if (p == 0) { kkH = 2999; n = 186; }
    else        { kkH = 3014 - LB*p; n = LB; }

    {
        const int nc = n/20, rem = n - nc*20;
        float A[20], B[20], C[20];
#define LDBc(BUF, c) { _Pragma("unroll") \
        for (int j = 0; j < 20; ++j) BUF[j] = ycol[(size_t)(kkH-19-20*(c)+j)*SEQ]; }
#define CHBc(BUF, c) { _Pragma("unroll") \
        for (int j = 19; j >= 0; --j) { float o; FSTEP((double)BUF[j], o); BUF[j] = o; } \
        _Pragma("unroll") \
        for (int j = 0; j < 20; ++j) ycol[(size_t)(kkH-19-20*(c)+j)*SEQ] = BUF[j]; }
        if (nc > 0) LDBc(A, 0); if (nc > 1) LDBc(B, 1); if (nc > 2) LDBc(C, 2);
        for (int g = 0; g < nc; g += 3) {
            CHBc(A, g); if (g+3 < nc) LDBc(A, g+3);
            if (g+1 < nc) { CHBc(B, g+1); if (g+4 < nc) LDBc(B, g+4); }
            if (g+2 < nc) { CHBc(C, g+2); if (g+5 < nc) LDBc(C, g+5); }
        }
        if (rem) {
            float T[19];
            #pragma unroll
            for (int j = 0; j < 19; ++j) if (j < rem) T[j] = ycol[(size_t)(kkH-20*nc-j)*SEQ];
            #pragma unroll
            for (int j = 0; j < 19; ++j) if (j < rem) {
                float o; FSTEP((double)T[j], o); ycol[(size_t)(kkH-20*nc-j)*SEQ] = o;
            }
        }
#undef LDBc
#undef CHBc
    }
    double* ze = Zeb + (((size_t)f*NSEG + p)*64 + b)*4;
    ze[0] = z0; ze[1] = z1; ze[2] = z2; ze[3] = z3;
}

// ---------------- k_corr_bwd ----------------------------------------------
__global__ __launch_bounds__(64) void k_corr_bwd(
    float* Pt, const double* __restrict__ H, const double* __restrict__ Zb)
{
    const int f = blockIdx.x, p = blockIdx.y + 1, b = threadIdx.x;
    const double* zp = Zb + (((size_t)f*NSEG + p)*64 + b)*4;
    const double w0 = zp[0], w1 = zp[1], w2 = zp[2], w3 = zp[3];
    const double* Hf = H + (size_t)f*LF*4;
    float* ycol = Pt + 64 + (size_t)f*64 + b;
    const int q0 = p*LB;
    #pragma unroll 4
    for (int j = 0; j < LB; ++j) {
        const int kk = 3014 - (q0 + j);
        double corr = Hf[j*4+0]*w0 + Hf[j*4+1]*w1 + Hf[j*4+2]*w2 + Hf[j*4+3]*w3;
        float* d = &ycol[(size_t)kk*SEQ];
        *d = (float)((double)*d + corr);
    }
}
#undef FSTEP
#undef COEFS

// ---------------- Kernel 2a: split-K GEMM partials -------------------------
__global__ __launch_bounds__(256) void k_ugemm(
    const float* __restrict__ Pt, const float* __restrict__ W1,
    float* __restrict__ Up)
{
    __shared__ float As[KC2*LDB];
    __shared__ float Bs[KC2*LDB];
    const int tid = threadIdx.x;
    const int rq = blockIdx.x, hq = blockIdx.y, ks = blockIdx.z;
    const int r0 = rq*128, h0 = hq*128;
    const int tg = tid & 15, ig = tid >> 4;

    float acc[8][8] = {};

    for (int c = 0; c < KPB/KC2; ++c) {
        const int k0 = ks*KPB + c*KC2;
        __syncthreads();
        for (int q = tid; q < KC2*32; q += 256) {
            const int kq = q >> 5;
            const int r4 = (q & 31) << 2;
            const float* psrc = Pt + (size_t)(k0+kq)*SEQ;
            float4 a;
            if (r0 + r4 + 3 < SEQ) a = *(const float4*)(psrc + r0 + r4);
            else {
                a.x = psrc[min(r0+r4+0, SEQ-1)];
                a.y = psrc[min(r0+r4+1, SEQ-1)];
                a.z = psrc[min(r0+r4+2, SEQ-1)];
                a.w = psrc[min(r0+r4+3, SEQ-1)];
            }
            *(float4*)&As[kq*LDB + r4] = a;
            float4 b = *(const float4*)(W1 + (size_t)(k0+kq)*NH + h0 + r4);
            *(float4*)&Bs[kq*LDB + r4] = b;
        }
        __syncthreads();
        #pragma unroll 5
        for (int k = 0; k < KC2; ++k) {
            float4 alo = *(const float4*)&As[k*LDB + tg*8];
            float4 ahi = *(const float4*)&As[k*LDB + tg*8 + 4];
            float4 blo = *(const float4*)&Bs[k*LDB + ig*8];
            float4 bhi = *(const float4*)&Bs[k*LDB + ig*8 + 4];
            float a[8] = {alo.x,alo.y,alo.z,alo.w,ahi.x,ahi.y,ahi.z,ahi.w};
            float b[8] = {blo.x,blo.y,blo.z,blo.w,bhi.x,bhi.y,bhi.z,bhi.w};
            #pragma unroll
            for (int mt = 0; mt < 8; ++mt)
                #pragma unroll
                for (int nn = 0; nn < 8; ++nn)
                    acc[mt][nn] = fmaf(a[mt], b[nn], acc[mt][nn]);
        }
    }

    float* up = Up + (size_t)ks*UPROWS*NH;
    #pragma unroll
    for (int mt = 0; mt < 8; ++mt) {
        const int r = r0 + tg*8 + mt;
        if (r < SEQ) {
            *(float4*)&up[(size_t)r*NH + h0 + ig*8]
                = make_float4(acc[mt][0], acc[mt][1], acc[mt][2], acc[mt][3]);
            *(float4*)&up[(size_t)r*NH + h0 + ig*8 + 4]
                = make_float4(acc[mt][4], acc[mt][5], acc[mt][6], acc[mt][7]);
        }
    }
}

// ---------------- Kernel 2b: reduce partials -------------------------------
__global__ __launch_bounds__(256) void k_ured(
    const float* __restrict__ Up, const float* __restrict__ b1,
    const float* __restrict__ w2, float* __restrict__ U)
{
    const int e = blockIdx.x*256 + threadIdx.x;
    const int r = e >> 6;
    const int h = (e & 63) << 2;
    float4 s = *(const float4*)(Up + (size_t)r*NH + h);
    #pragma unroll
    for (int ks = 1; ks < KS; ++ks) {
        float4 t = *(const float4*)(Up + (size_t)ks*UPROWS*NH + (size_t)r*NH + h);
        s.x += t.x; s.y += t.y; s.z += t.z; s.w += t.w;
    }
    float4 bv = *(const float4*)(b1 + h);
    float4 wv = *(const float4*)(w2 + h);
    float t0 = tanhf(s.x + bv.x), t1 = tanhf(s.y + bv.y),
          t2 = tanhf(s.z + bv.z), t3 = tanhf(s.w + bv.w);
    *(float4*)&U[(size_t)r*NH + h]
        = make_float4((1.f - t0*t0)*wv.x, (1.f - t1*t1)*wv.y,
                      (1.f - t2*t2)*wv.z, (1.f - t3*t3)*wv.w);
}

__device__ __forceinline__ float rowval_pt(const float* __restrict__ Pt,
                                           int ii, int bb, int t)
{
    if (ii <= 2)  return Pt[(size_t)t*SEQ + bb];
    if (ii <= 99) return Pt[(size_t)t*SEQ + 64 + (ii-3)*64 + bb];
    return 0.f;
}

// ---------------- Kernel 3: GEMM + fused V-build + epilogue ---------------
__global__ __launch_bounds__(256) void k_out(
    const float* __restrict__ Pt, const float* __restrict__ W1,
    const float* __restrict__ U, const int* __restrict__ freq_index,
    float* __restrict__ out)
{
    __shared__ float As[KCO*LDA];
    __shared__ float Vs[KCO*LDA];
    __shared__ int  inv[NI];
    const int tid = threadIdx.x;
    const int tb  = blockIdx.x;
    const int nb  = blockIdx.y;
    if (tid < NI) inv[freq_index[tid]] = tid;

    const int tg = tid & 15;
    const int ig = tid >> 4;
    const int t0 = tb*128, n0 = nb*128;
    const int sk = tid & 7;
    const int sr = tid >> 3;

    int ra[4], rb[4];
    #pragma unroll
    for (int m = 0; m < 4; ++m) {
        int n  = n0 + sr + 32*m;
        int bb = n / 100;
        int ii = n - bb*100;
        ra[m] = (ii <= 2) ? bb : 64 + (ii-3)*64 + bb;
        rb[m] = (ii+1 <= 2) ? bb : ((ii+1 <= 99) ? 64 + (ii-2)*64 + bb : SEQ);
    }

    float acc[8][8] = {};

    for (int c = 0; c < 8; ++c) {
        const int k0 = c*KCO;
        __syncthreads();
        #pragma unroll
        for (int m = 0; m < 4; ++m) {
            int row = sr + 32*m;
            int tg_ = t0 + row; if (tg_ > T_LEN-1) tg_ = T_LEN-1;
            float4 a = *(const float4*)(W1 + (size_t)tg_*NH + k0 + sk*4);
            As[(sk*4+0)*LDA + row] = a.x;
            As[(sk*4+1)*LDA + row] = a.y;
            As[(sk*4+2)*LDA + row] = a.z;
            As[(sk*4+3)*LDA + row] = a.w;
            float4 ua = *(const float4*)(U + (size_t)ra[m]*NH + k0 + sk*4);
            float4 ub = *(const float4*)(U + (size_t)rb[m]*NH + k0 + sk*4);
            Vs[(sk*4+0)*LDA + row] = 0.5f*(ua.x + ub.x);
            Vs[(sk*4+1)*LDA + row] = 0.5f*(ua.y + ub.y);
            Vs[(sk*4+2)*LDA + row] = 0.5f*(ua.z + ub.z);
            Vs[(sk*4+3)*LDA + row] = 0.5f*(ua.w + ub.w);
        }
        __syncthreads();
        #pragma unroll 4
        for (int k = 0; k < KCO; ++k) {
            float4 alo = *(const float4*)&As[k*LDA + tg*8];
            float4 ahi = *(const float4*)&As[k*LDA + tg*8 + 4];
            float4 vlo = *(const float4*)&Vs[k*LDA + ig*8];
            float4 vhi = *(const float4*)&Vs[k*LDA + ig*8 + 4];
            float a[8] = {alo.x, alo.y, alo.z, alo.w, ahi.x, ahi.y, ahi.z, ahi.w};
            float v[8] = {vlo.x, vlo.y, vlo.z, vlo.w, vhi.x, vhi.y, vhi.z, vhi.w};
            #pragma unroll
            for (int mt = 0; mt < 8; ++mt)
                #pragma unroll
                for (int nn = 0; nn < 8; ++nn)
                    acc[mt][nn] = fmaf(a[mt], v[nn], acc[mt][nn]);
        }
    }

    #pragma unroll
    for (int mt = 0; mt < 8; ++mt) {
        const int t = t0 + tg*8 + mt;
        if (t < T_LEN) {
            float rv = 0.f;
            #pragma unroll
            for (int nn = 0; nn < 8; ++nn) {
                const int n  = n0 + ig*8 + nn;
                const int bb = n / 100;
                const int ii = n - bb*100;
                if (nn == 0 || ii == 0) rv = rowval_pt(Pt, ii, bb, t);
                float rvn = rowval_pt(Pt, ii+1, bb, t);
                out[(size_t)bb*T_LEN*NI + (size_t)t*NI + inv[ii]]
                    = acc[mt][nn] * (rv - rvn);
                rv = rvn;
            }
        }
    }
}

extern "C" void kernel_launch(void* const* d_in, const int* in_sizes, int n_in,
                              void* d_out, int out_size, void* d_ws, size_t ws_size,
                              hipStream_t stream) {
    const float* x      = (const float*)d_in[0];
    const float* b_all  = (const float*)d_in[1];
    const float* a_all  = (const float*)d_in[2];
    const float* zi_all = (const float*)d_in[3];
    const float* W1     = (const float*)d_in[4];
    const float* b1     = (const float*)d_in[5];
    const float* w2     = (const float*)d_in[6];
    const int*   fidx   = (const int*)d_in[7];
    float* out = (float*)d_out;

    float* Pt = (float*)d_ws;                       // [3000][6336] k-major
    float* U  = Pt + (size_t)T_LEN * SEQ;           // [6337][256]

    // filtfilt scratch lives in d_out (fully consumed before k_ugemm reuses it)
    double* Hd  = (double*)d_out;                   // [97][202][4]
    double* Mfd = Hd + (size_t)NF*LF*4;             // [97][16]
    double* Mbd = Mfd + NF*16;
    double* Zef = Mbd + NF*16;                      // [97][15][64][4]
    double* Zeb = Zef + (size_t)NF*NSEG*64*4;
    double* Zfd = Zeb + (size_t)NF*NSEG*64*4;
    double* Zbd = Zfd + (size_t)NF*NSEG*64*4;
    float*  YRb = (float*)(Zbd + (size_t)NF*NSEG*64*4);   // [97][15][64]
    float*  Up  = out;                              // split-K partials (52 MB)

    hipLaunchKernelGGL(k_prep, dim3((T_LEN+63)/64), dim3(256), 0, stream,
                       x, b1, w2, Pt, U);
    hipLaunchKernelGGL(k_hom, dim3(7), dim3(64), 0, stream,
                       a_all, Hd, Mbd, Mfd);
    hipLaunchKernelGGL(k_seg_fwd, dim3(NF, NSEG), dim3(64), 0, stream,
                       Pt, b_all, a_all, zi_all, YRb, Zef);
    hipLaunchKernelGGL(k_stitch, dim3(NF), dim3(64), 0, stream,
                       Zef, Mfd, Zfd);
    hipLaunchKernelGGL(k_corr_fwd, dim3(NF, 14), dim3(64), 0, stream,
                       Pt, YRb, Hd, Zfd);
    hipLaunchKernelGGL(k_seg_bwd, dim3(NF, NSEG), dim3(64), 0, stream,
                       Pt, b_all, a_all, zi_all, YRb, Zeb);
    hipLaunchKernelGGL(k_stitch, dim3(NF), dim3(64), 0, stream,
                       Zeb, Mbd, Zbd);
    hipLaunchKernelGGL(k_corr_bwd, dim3(NF, 14), dim3(64), 0, stream,
                       Pt, Hd, Zbd);
    hipLaunchKernelGGL(k_ugemm, dim3(50, 2, KS), dim3(256), 0, stream,
                       Pt, W1, Up);
    hipLaunchKernelGGL(k_ured, dim3(SEQ*64/256), dim3(256), 0, stream,
                       Up, b1, w2, U);
    hipLaunchKernelGGL(k_out, dim3((T_LEN+127)/128, (NB*NI)/128), dim3(256), 0, stream,
                       Pt, W1, U, fidx, out);
}